// Round 9
// baseline (1042.945 us; speedup 1.0000x reference)
//
#include <hip/hip_runtime.h>
#include <cstddef>

// Problem constants
#define NB 16
#define NVOX 128
#define NPT 1920
#define NCHUNK 4096            // 16 batches x 256 chunks x 8 pairs
#define NTICK (NB + NCHUNK)

static __device__ __forceinline__ float2 f2(float a, float b) {
    float2 r; r.x = a; r.y = b; return r;
}

// Per-axis composed 7-tap coefficients (A^3 of zero-padded 3-tap average):
// interior [1,3,6,7,6,3,1]/27; boundary rows via cm1/c0/cp1 overrides.
__device__ __forceinline__ void coef(int g, float& cm1, float& c0, float& cp1)
{
    cm1 = (g == 1 || g == 127) ? 5.f : 6.f;
    c0  = (g == 0 || g == 127) ? 4.f : 7.f;
    cp1 = (g == 0 || g == 126) ? 5.f : 6.f;
}

// ---------------------------------------------------------------------------
// LDS overlay: tail work and tile work never coexist in a block.
// Tail = 55,168 B; tile = 34,608 B. Union ~55.2 KB -> 2 blocks/CU,
// grid 512 fully co-resident (not required for correctness).
// ---------------------------------------------------------------------------
struct SMemTail {
    float x1s[1920];          // stage1 output, flat (64,30)
    float h3[7680];           // relu'd IN3; first 2048 double as staged q
    float m4s[16], r4s[16];
    int cnt[2048];            // per-pair incidence counts
    int off[2048];            // CSR fill cursors
    int gsum[64];
};
struct SMemTile {
    float2 raw[4312];         // 22x14x14 splat tile
    int rpl[9];               // chunk's CSR row pointers
    int act[8], inact[8];
    int na, ni;
};
union __align__(16) SMemU {
    SMemTail a;
    SMemTile b;
};

// ---------------------------------------------------------------------------
// Single fused kernel, 512 blocks x 512 threads, dynamic ticket scheduler.
//   ticket < 16      : run batch tail (MLP -> pts -> CSR), release flag[b]
//   ticket >= 16     : 8-pair chunk; poll flag[batch]; inactive pairs ->
//                      exact 4 KB zero stores; active pairs -> CSR splat +
//                      in-place register-rolling z/y/x smooth + divide.
// Deadlock-free: tail tickets are grabbed by the first 16 RUNNING blocks,
// so flag producers are always scheduled; pollers' batches always complete.
// Every output byte has exactly ONE writer (inactive XOR active path).
// ---------------------------------------------------------------------------
__global__ __launch_bounds__(512)
void mega(const float* __restrict__ q, const float* __restrict__ w1,
          const float* __restrict__ b1, const float* __restrict__ qval,
          const float* __restrict__ w2, const float* __restrict__ b2,
          const float* __restrict__ w3, const float* __restrict__ b3,
          const float* __restrict__ w4, const float* __restrict__ b4,
          const float* __restrict__ w5, const float* __restrict__ b5,
          float4* __restrict__ pts, int* __restrict__ rp,
          int* __restrict__ ent, int* __restrict__ flag,
          int* __restrict__ ticket, float* __restrict__ out)
{
    __shared__ SMemU S;
    __shared__ int sh_tk;
    const int t = threadIdx.x;

    while (true) {
        if (t == 0) sh_tk = atomicAdd(ticket, 1);
        __syncthreads();
        const int tk = sh_tk;
        __syncthreads();
        if (tk >= NTICK) break;

        if (tk < NB) {
            // ===================== TAIL (batch b = tk) =====================
            const int b = tk;
            float* qs = S.a.h3;   // overlay: h3 not live until after stage1

            for (int u = t; u < 2048; u += 512) {
                qs[u] = q[b * 2048 + u];
                S.a.cnt[u] = 0;
            }
            __syncthreads();

            // stage1: x1[(o,l)] = b1[o] + sum_i w1[o,i] * q[b, i*8+l]
            for (int u = t; u < 1920; u += 512) {
                int o = u >> 3, l = u & 7;
                const float4* wr = (const float4*)(w1 + o * 256);
                float acc = 0.f;
                #pragma unroll 8
                for (int i4 = 0; i4 < 64; ++i4) {
                    float4 w = wr[i4];
                    int base = i4 * 32 + l;
                    acc = fmaf(w.x, qs[base],      acc);
                    acc = fmaf(w.y, qs[base + 8],  acc);
                    acc = fmaf(w.z, qs[base + 16], acc);
                    acc = fmaf(w.w, qs[base + 24], acc);
                }
                S.a.x1s[u] = b1[o] + acc;
            }
            __syncthreads();   // qs dead; h3 live

            // wave-per-channel chain: 8 waves x 2 channels (c3, c3+8)
            const int l = t & 63;
            const int c1l = l >> 4;
            const int p16 = l & 15;
            const bool hasb = (p16 < 14);
            for (int cc = 0; cc < 2; ++cc) {
                const int c3 = (t >> 6) + 8 * cc;
                const int c1 = 4 * c3 + c1l;
                const float* xrow = S.a.x1s + c1 * 30;
                float a0 = xrow[p16];
                float a1 = hasb ? xrow[p16 + 16] : 0.f;

                // IN1 over 30: butterfly within 16-lane channel group
                float s = a0 + a1, s2 = a0 * a0 + a1 * a1;
                #pragma unroll
                for (int m = 1; m <= 8; m <<= 1) {
                    s  += __shfl_xor(s,  m);
                    s2 += __shfl_xor(s2, m);
                }
                float mean = s * (1.f / 30.f);
                float var  = s2 * (1.f / 30.f) - mean * mean;
                float rstd = rsqrtf(var + 1e-5f);
                a0 = fmaxf((a0 - mean) * rstd, 0.f);
                a1 = fmaxf((a1 - mean) * rstd, 0.f);

                // stage2: grouped conv 64->128
                const float w20 = w2[c1 * 2 + 0], w21 = w2[c1 * 2 + 1];
                const float b20 = b2[c1 * 2 + 0], b21 = b2[c1 * 2 + 1];
                float y00 = fmaf(a0, w20, b20), y01 = fmaf(a0, w21, b21);
                float y10 = fmaf(a1, w20, b20), y11 = fmaf(a1, w21, b21);

                // IN2 over 120: butterfly within 32-lane half
                float u1 = y00 + y01 + (hasb ? (y10 + y11) : 0.f);
                float u2 = y00 * y00 + y01 * y01
                         + (hasb ? (y10 * y10 + y11 * y11) : 0.f);
                #pragma unroll
                for (int m = 1; m <= 16; m <<= 1) {
                    u1 += __shfl_xor(u1, m);
                    u2 += __shfl_xor(u2, m);
                }
                mean = u1 * (1.f / 120.f);
                var  = u2 * (1.f / 120.f) - mean * mean;
                rstd = rsqrtf(var + 1e-5f);
                y00 = fmaxf((y00 - mean) * rstd, 0.f);
                y01 = fmaxf((y01 - mean) * rstd, 0.f);
                y10 = fmaxf((y10 - mean) * rstd, 0.f);
                y11 = fmaxf((y11 - mean) * rstd, 0.f);

                // stage3: grouped conv 32->64
                const int c2 = c1 >> 1;
                const float w30 = w3[c2 * 2 + 0], w31 = w3[c2 * 2 + 1];
                const float b30 = b3[c2 * 2 + 0], b31 = b3[c2 * 2 + 1];
                float z000 = fmaf(y00, w30, b30), z001 = fmaf(y00, w31, b31);
                float z010 = fmaf(y01, w30, b30), z011 = fmaf(y01, w31, b31);
                float z100 = fmaf(y10, w30, b30), z101 = fmaf(y10, w31, b31);
                float z110 = fmaf(y11, w30, b30), z111 = fmaf(y11, w31, b31);

                // IN3 over 480: full-wave butterfly
                float v1 = z000 + z001 + z010 + z011
                         + (hasb ? (z100 + z101 + z110 + z111) : 0.f);
                float v2 = z000 * z000 + z001 * z001 + z010 * z010 + z011 * z011
                         + (hasb ? (z100 * z100 + z101 * z101
                                  + z110 * z110 + z111 * z111) : 0.f);
                #pragma unroll
                for (int m = 1; m <= 32; m <<= 1) {
                    v1 += __shfl_xor(v1, m);
                    v2 += __shfl_xor(v2, m);
                }
                mean = v1 * (1.f / 480.f);
                var  = v2 * (1.f / 480.f) - mean * mean;
                rstd = rsqrtf(var + 1e-5f);

                // normalize+relu -> h3; accumulate sums for IN4 stats
                const int qb0 = (c1l >> 1) * 240;
                const int pb0 = (c1l & 1) * 60;
                float* hw = S.a.h3 + c3 * 480;
                float s4 = 0.f, q4 = 0.f;
                {
                    float v;
                    v = fmaxf((z000 - mean) * rstd, 0.f); hw[qb0 +       pb0 +      p16] = v; s4 += v; q4 += v * v;
                    v = fmaxf((z001 - mean) * rstd, 0.f); hw[qb0 + 120 + pb0 +      p16] = v; s4 += v; q4 += v * v;
                    v = fmaxf((z010 - mean) * rstd, 0.f); hw[qb0 +       pb0 + 30 + p16] = v; s4 += v; q4 += v * v;
                    v = fmaxf((z011 - mean) * rstd, 0.f); hw[qb0 + 120 + pb0 + 30 + p16] = v; s4 += v; q4 += v * v;
                    if (hasb) {
                        v = fmaxf((z100 - mean) * rstd, 0.f); hw[qb0 +       pb0 +      p16 + 16] = v; s4 += v; q4 += v * v;
                        v = fmaxf((z101 - mean) * rstd, 0.f); hw[qb0 + 120 + pb0 +      p16 + 16] = v; s4 += v; q4 += v * v;
                        v = fmaxf((z110 - mean) * rstd, 0.f); hw[qb0 +       pb0 + 30 + p16 + 16] = v; s4 += v; q4 += v * v;
                        v = fmaxf((z111 - mean) * rstd, 0.f); hw[qb0 + 120 + pb0 + 30 + p16 + 16] = v; s4 += v; q4 += v * v;
                    }
                }
                #pragma unroll
                for (int m = 1; m <= 32; m <<= 1) {
                    s4 += __shfl_xor(s4, m);
                    q4 += __shfl_xor(q4, m);
                }
                if (l == 0) {
                    float sum4 = 0.f, sq4 = 0.f;
                    #pragma unroll
                    for (int j = 0; j < 4; ++j) {
                        float ww = w4[c3 * 4 + j], bb = b4[c3 * 4 + j];
                        sum4 += ww * s4 + 480.f * bb;
                        sq4  += ww * ww * q4 + 2.f * ww * bb * s4 + 480.f * bb * bb;
                    }
                    float m4 = sum4 * (1.f / 1920.f);
                    float var4 = sq4 * (1.f / 1920.f) - m4 * m4;
                    S.a.m4s[c3] = m4; S.a.r4s[c3] = rsqrtf(var4 + 1e-5f);
                }
            }
            __syncthreads();

            // per-point: stage4/5 + tanh + emit + COUNT pair incidences
            int x0s[4], y0s[4], z0s[4];
            #pragma unroll
            for (int k = 0; k < 4; ++k) {
                int p = t + k * 512;
                if (p >= NPT) break;
                int j = p / 480;
                int pp = p - j * 480;
                float a0e = b5[0], a1e = b5[1], a2e = b5[2];
                #pragma unroll
                for (int c = 0; c < 16; ++c) {
                    float xv = S.a.h3[c * 480 + pp];
                    float x4 = fmaf(xv, w4[c * 4 + j], b4[c * 4 + j]);
                    float h  = fmaxf((x4 - S.a.m4s[c]) * S.a.r4s[c], 0.f);
                    a0e = fmaf(w5[c],      h, a0e);
                    a1e = fmaf(w5[16 + c], h, a1e);
                    a2e = fmaf(w5[32 + c], h, a2e);
                }
                float px = tanhf(a0e) * 64.f + 63.5f;
                float py = tanhf(a1e) * 64.f + 63.5f;
                float pz = tanhf(a2e) * 64.f + 63.5f;
                float val = 1.f / (1.f + expf(-qval[p]));

                float4 pv; pv.x = px; pv.y = py; pv.z = pz; pv.w = val;
                pts[b * NPT + p] = pv;

                int x0 = (int)floorf(px), y0 = (int)floorf(py), z0 = (int)floorf(pz);
                x0s[k] = x0; y0s[k] = y0; z0s[k] = z0;
                int xlo = max(0, x0 - 3), xhi = min(127, x0 + 4);
                int ylo = max(0, y0 - 3), yhi = min(127, y0 + 4);
                int zlo = max(0, z0 - 3), zhi = min(127, z0 + 4);
                int pxl = xlo >> 4, pxh = xhi >> 4;
                int tyl = ylo >> 3, tyh = yhi >> 3;
                int tzl = zlo >> 3, tzh = zhi >> 3;
                for (int tz = tzl; tz <= tzh; ++tz)
                    for (int ty = tyl; ty <= tyh; ++ty)
                        for (int px2 = pxl; px2 <= pxh; ++px2)
                            atomicAdd(&S.a.cnt[(tz * 16 + ty) * 8 + px2], 1);
            }
            __syncthreads();

            // prefix-sum cnt -> rp (global) + fill cursors
            if (t < 64) {
                int s = 0;
                for (int i = 0; i < 32; ++i) s += S.a.cnt[t * 32 + i];
                S.a.gsum[t] = s;
            }
            __syncthreads();
            if (t == 0) {
                int s = 0;
                for (int i = 0; i < 64; ++i) { int v = S.a.gsum[i]; S.a.gsum[i] = s; s += v; }
            }
            __syncthreads();
            if (t < 64) {
                int s = S.a.gsum[t];
                for (int i = 0; i < 32; ++i) {
                    int u = t * 32 + i;
                    rp[b * 2049 + u] = s;
                    S.a.off[u] = s;
                    s += S.a.cnt[u];
                }
                if (t == 63) rp[b * 2049 + 2048] = s;
            }
            __syncthreads();

            // fill CSR entries
            #pragma unroll
            for (int k = 0; k < 4; ++k) {
                int p = t + k * 512;
                if (p >= NPT) break;
                int x0 = x0s[k], y0 = y0s[k], z0 = z0s[k];
                int xlo = max(0, x0 - 3), xhi = min(127, x0 + 4);
                int ylo = max(0, y0 - 3), yhi = min(127, y0 + 4);
                int zlo = max(0, z0 - 3), zhi = min(127, z0 + 4);
                int pxl = xlo >> 4, pxh = xhi >> 4;
                int tyl = ylo >> 3, tyh = yhi >> 3;
                int tzl = zlo >> 3, tzh = zhi >> 3;
                for (int tz = tzl; tz <= tzh; ++tz)
                    for (int ty = tyl; ty <= tyh; ++ty)
                        for (int px2 = pxl; px2 <= pxh; ++px2) {
                            int pos = atomicAdd(&S.a.off[(tz * 16 + ty) * 8 + px2], 1);
                            ent[b * 16384 + pos] = p;
                        }
            }
            __syncthreads();

            if (t == 0) {
                __threadfence();   // release pts/rp/ent
                __hip_atomic_store(flag + b, 1, __ATOMIC_RELEASE,
                                   __HIP_MEMORY_SCOPE_AGENT);
            }
            continue;
        }

        // ===================== CHUNK (8 pairs) =====================
        const int c = tk - NB;
        const int b = c & 15;                 // round-robin across batches
        const int u0 = (c >> 4) << 3;         // first pair of this chunk

        if (t == 0) {
            while (__hip_atomic_load(flag + b, __ATOMIC_ACQUIRE,
                                     __HIP_MEMORY_SCOPE_AGENT) == 0)
                __builtin_amdgcn_s_sleep(32);
        }
        __syncthreads();
        __threadfence();

        if (t < 9) S.b.rpl[t] = rp[b * 2049 + u0 + t];
        if (t == 9) { S.b.na = 0; }
        if (t == 10) { S.b.ni = 0; }
        __syncthreads();
        if (t == 0) {
            int na = 0, ni = 0;
            #pragma unroll
            for (int i = 0; i < 8; ++i) {
                if (S.b.rpl[i + 1] > S.b.rpl[i]) S.b.act[na++] = i;
                else S.b.inact[ni++] = i;
            }
            S.b.na = na; S.b.ni = ni;
        }
        __syncthreads();

        // inactive pairs: exact 4 KB zero stores (sole writer of these bytes)
        const int ni = S.b.ni;
        for (int i = t; i < ni * 256; i += 512) {
            int u = u0 + S.b.inact[i >> 8];
            int o = i & 255;
            int x4 = o & 3, y = (o >> 2) & 7, z = o >> 5;
            int Tx = (u & 7) * 16, Ty = ((u >> 3) & 15) * 8, Tz = ((u >> 7) & 15) * 8;
            float* ob = out + (((size_t)(b * NVOX + Tz) * NVOX + Ty) * NVOX + Tx);
            *(float4*)&ob[((size_t)z * NVOX + y) * NVOX + x4 * 4] =
                make_float4(0.f, 0.f, 0.f, 0.f);
        }

        // active pairs: CSR splat + in-place register-rolling smooth
        const int na = S.b.na;
        for (int a = 0; a < na; ++a) {
            const int pi = S.b.act[a];
            const int u = u0 + pi;
            const int Tx = (u & 7) * 16;
            const int Ty = ((u >> 3) & 15) * 8;
            const int Tz = ((u >> 7) & 15) * 8;
            const int base = S.b.rpl[pi];
            const int endp = S.b.rpl[pi + 1];
            float* ob = out + (((size_t)(b * NVOX + Tz) * NVOX + Ty) * NVOX + Tx);
            float2* raw = S.b.raw;

            {   // zero the LDS tile
                float4* rz = (float4*)raw;
                for (int v = t; v < 2156; v += 512)
                    rz[v] = make_float4(0.f, 0.f, 0.f, 0.f);
            }
            __syncthreads();

            // CSR splat: only this tile's points
            for (int e = base + t; e < endp; e += 512) {
                int p = ent[b * 16384 + e];
                float4 pt = pts[b * NPT + p];
                float x0f = floorf(pt.x), y0f = floorf(pt.y), z0f = floorf(pt.z);
                int x0 = (int)x0f, y0 = (int)y0f, z0 = (int)z0f;
                int lx0 = x0 - Tx + 3, ly0 = y0 - Ty + 3, lz0 = z0 - Tz + 3;
                float fx = pt.x - x0f, fy = pt.y - y0f, fz = pt.z - z0f;
                float val = pt.w;
                #pragma unroll
                for (int dz = 0; dz < 2; ++dz) {
                    int zi = z0 + dz, lz = lz0 + dz;
                    if ((unsigned)zi >= 128u || (unsigned)lz >= 14u) continue;
                    float wz = dz ? fz : 1.f - fz;
                    #pragma unroll
                    for (int dy = 0; dy < 2; ++dy) {
                        int yi = y0 + dy, ly = ly0 + dy;
                        if ((unsigned)yi >= 128u || (unsigned)ly >= 14u) continue;
                        float wy = dy ? fy : 1.f - fy;
                        #pragma unroll
                        for (int dx = 0; dx < 2; ++dx) {
                            int xi = x0 + dx, lx = lx0 + dx;
                            if ((unsigned)xi >= 128u || (unsigned)lx >= 22u) continue;
                            float w = (dx ? fx : 1.f - fx) * wy * wz;
                            float2* cell = &raw[(lz * 14 + ly) * 22 + lx];
                            atomicAdd(&cell->x, w * val);
                            atomicAdd(&cell->y, w);
                        }
                    }
                }
            }
            __syncthreads();

            // z-pass IN PLACE: columns (ly,lx), stride 308
            if (t < 308) {
                float2 w0 = raw[t],            w1_ = raw[t + 308],
                       w2_ = raw[t + 2 * 308], w3_ = raw[t + 3 * 308],
                       w4_ = raw[t + 4 * 308], w5_ = raw[t + 5 * 308],
                       w6_ = raw[t + 6 * 308];
                #pragma unroll
                for (int z = 0; z < 8; ++z) {
                    float cm1, c0, cp1; coef(Tz + z, cm1, c0, cp1);
                    float sx = (w0.x + w6_.x) + 3.f * (w1_.x + w5_.x)
                             + cm1 * w2_.x + c0 * w3_.x + cp1 * w4_.x;
                    float sy = (w0.y + w6_.y) + 3.f * (w1_.y + w5_.y)
                             + cm1 * w2_.y + c0 * w3_.y + cp1 * w4_.y;
                    float2 nx2 = raw[t + ((z < 7) ? z + 7 : 7) * 308];
                    raw[t + z * 308] = f2(sx * (1.f / 27.f), sy * (1.f / 27.f));
                    w0 = w1_; w1_ = w2_; w2_ = w3_; w3_ = w4_; w4_ = w5_; w5_ = w6_; w6_ = nx2;
                }
            }
            __syncthreads();

            // y-pass IN PLACE: columns (z,lx), z<8, stride 22
            if (t < 176) {
                int z = t / 22, lx = t - z * 22;
                float2* base2 = &raw[z * 308 + lx];
                float2 w0 = base2[0],       w1_ = base2[22],
                       w2_ = base2[2 * 22], w3_ = base2[3 * 22],
                       w4_ = base2[4 * 22], w5_ = base2[5 * 22],
                       w6_ = base2[6 * 22];
                #pragma unroll
                for (int y = 0; y < 8; ++y) {
                    float cm1, c0, cp1; coef(Ty + y, cm1, c0, cp1);
                    float sx = (w0.x + w6_.x) + 3.f * (w1_.x + w5_.x)
                             + cm1 * w2_.x + c0 * w3_.x + cp1 * w4_.x;
                    float sy = (w0.y + w6_.y) + 3.f * (w1_.y + w5_.y)
                             + cm1 * w2_.y + c0 * w3_.y + cp1 * w4_.y;
                    float2 nx2 = base2[((y < 7) ? y + 7 : 7) * 22];
                    base2[y * 22] = f2(sx * (1.f / 27.f), sy * (1.f / 27.f));
                    w0 = w1_; w1_ = w2_; w2_ = w3_; w3_ = w4_; w4_ = w5_; w5_ = w6_; w6_ = nx2;
                }
            }
            __syncthreads();

            // x-pass + division: 2 threads per (z,y) row
            if (t < 128) {
                int row = t >> 1, hx = t & 1;
                int z = row >> 3, y = row & 7;
                const float2* aa = &raw[z * 308 + y * 22 + hx * 8];
                float2 w0 = aa[0], w1_ = aa[1], w2_ = aa[2], w3_ = aa[3],
                       w4_ = aa[4], w5_ = aa[5], w6_ = aa[6];
                float res[8];
                #pragma unroll
                for (int i = 0; i < 8; ++i) {
                    int x = hx * 8 + i;
                    float cm1, c0, cp1; coef(Tx + x, cm1, c0, cp1);
                    float sx = (w0.x + w6_.x) + 3.f * (w1_.x + w5_.x)
                             + cm1 * w2_.x + c0 * w3_.x + cp1 * w4_.x;
                    float sy = (w0.y + w6_.y) + 3.f * (w1_.y + w5_.y)
                             + cm1 * w2_.y + c0 * w3_.y + cp1 * w4_.y;
                    res[i] = (sx * (1.f / 27.f)) / (sy * (1.f / 27.f) + 0.001f);
                    float2 nx2 = aa[(i < 7) ? i + 7 : 13];
                    w0 = w1_; w1_ = w2_; w2_ = w3_; w3_ = w4_; w4_ = w5_; w5_ = w6_; w6_ = nx2;
                }
                float* orow = &ob[((size_t)z * NVOX + y) * NVOX + hx * 8];
                *(float4*)&orow[0] = make_float4(res[0], res[1], res[2], res[3]);
                *(float4*)&orow[4] = make_float4(res[4], res[5], res[6], res[7]);
            }
            __syncthreads();   // raw reused by next active / next chunk
        }
    }
}

// ---------------------------------------------------------------------------
extern "C" void kernel_launch(void* const* d_in, const int* in_sizes, int n_in,
                              void* d_out, int out_size, void* d_ws, size_t ws_size,
                              hipStream_t stream)
{
    const float* q    = (const float*)d_in[0];
    const float* qval = (const float*)d_in[1];
    const float* w1   = (const float*)d_in[2];
    const float* b1   = (const float*)d_in[3];
    const float* w2   = (const float*)d_in[4];
    const float* b2   = (const float*)d_in[5];
    const float* w3   = (const float*)d_in[6];
    const float* b3   = (const float*)d_in[7];
    const float* w4   = (const float*)d_in[8];
    const float* b4   = (const float*)d_in[9];
    const float* w5   = (const float*)d_in[10];
    const float* b5   = (const float*)d_in[11];
    float* out = (float*)d_out;

    // ws layout:
    //   [0,64)           flag[16]
    //   [64,128)         ticket (+pad)
    //   [128, 131264)    rp   (16 x 2049 ints)
    //   [131264,1179840) ent  (16 x 16384 ints)
    //   [1179840,1671360) pts (16 x 1920 float4)
    int*    flag   = (int*)d_ws;
    int*    ticket = (int*)((char*)d_ws + 64);
    int*    rp     = (int*)((char*)d_ws + 128);
    int*    ent    = (int*)((char*)d_ws + 131264);
    float4* pts    = (float4*)((char*)d_ws + 1179840);

    hipMemsetAsync(d_ws, 0, 128, stream);

    mega<<<512, 512, 0, stream>>>(q, w1, b1, qval, w2, b2, w3, b3,
                                  w4, b4, w5, b5, pts, rp, ent,
                                  flag, ticket, out);
}

// Round 10
// 226.872 us; speedup vs baseline: 4.5971x; 4.5971x over previous
//
#include <hip/hip_runtime.h>
#include <cstddef>

// Problem constants
#define NB 16
#define NVOX 128
#define NPT 1920

static __device__ __forceinline__ float2 f2(float a, float b) {
    float2 r; r.x = a; r.y = b; return r;
}

// Per-axis composed 7-tap coefficients (A^3 of zero-padded 3-tap average):
// interior [1,3,6,7,6,3,1]/27; boundary rows via cm1/c0/cp1 overrides.
__device__ __forceinline__ void coef(int g, float& cm1, float& c0, float& cp1)
{
    cm1 = (g == 1 || g == 127) ? 5.f : 6.f;
    c0  = (g == 0 || g == 127) ? 4.f : 7.f;
    cp1 = (g == 0 || g == 126) ? 5.f : 6.f;
}

// ---------------------------------------------------------------------------
// Zero the whole output at full write BW (~21 us @ ~80%); also resets the
// tile-list count (removes the hipMemsetAsync dispatch).
// ---------------------------------------------------------------------------
__global__ __launch_bounds__(256)
void zero_out(float4* __restrict__ out, int* __restrict__ count)
{
    if (blockIdx.x == 0 && threadIdx.x == 0) *count = 0;
    int idx = blockIdx.x * 2048 + threadIdx.x;
    #pragma unroll
    for (int i = 0; i < 8; ++i)
        out[idx + i * 256] = make_float4(0.f, 0.f, 0.f, 0.f);
}

// ---------------------------------------------------------------------------
// Tail (R4-verified): stage1 GEMM + wave-per-channel MLP + point gen +
// LDS-flag compaction into the global list. One block per batch, 1024 thr.
// ---------------------------------------------------------------------------
__global__ __launch_bounds__(1024)
void mega_tail(const float* __restrict__ q, const float* __restrict__ w1,
               const float* __restrict__ b1, const float* __restrict__ qval,
               const float* __restrict__ w2, const float* __restrict__ b2,
               const float* __restrict__ w3, const float* __restrict__ b3,
               const float* __restrict__ w4, const float* __restrict__ b4,
               const float* __restrict__ w5, const float* __restrict__ b5,
               float4* __restrict__ pts, int* __restrict__ count,
               int* __restrict__ list)
{
    __shared__ float x1s[1920];          // stage1 output, flat (64,30)
    __shared__ float h3[7680];           // relu'd IN3; first 2048 double as qs
    __shared__ float m4s[16], r4s[16];
    __shared__ unsigned char lflags[2048];   // tz16 * ty16 * px8 pair flags

    const int b = blockIdx.x;
    const int t = threadIdx.x;
    float* qs = h3;    // overlay: h3 not live until after stage1

    for (int u = t; u < 2048; u += 1024) {
        qs[u] = q[b * 2048 + u];
        lflags[u] = 0;
    }
    __syncthreads();

    // stage1: x1[(o,l)] = b1[o] + sum_i w1[o,i] * q[b, i*8+l]
    for (int u = t; u < 1920; u += 1024) {
        int o = u >> 3, l = u & 7;
        const float4* wr = (const float4*)(w1 + o * 256);
        float acc = 0.f;
        #pragma unroll 8
        for (int i4 = 0; i4 < 64; ++i4) {
            float4 w = wr[i4];
            int base = i4 * 32 + l;
            acc = fmaf(w.x, qs[base],      acc);
            acc = fmaf(w.y, qs[base + 8],  acc);
            acc = fmaf(w.z, qs[base + 16], acc);
            acc = fmaf(w.w, qs[base + 24], acc);
        }
        x1s[u] = b1[o] + acc;
    }
    __syncthreads();   // qs dead from here; h3 live

    // wave-per-channel chain: wave w == final channel c3
    const int l = t & 63;
    const int c1l = l >> 4;
    const int p16 = l & 15;
    const bool hasb = (p16 < 14);    // second element p16+16 < 30
    {
        const int c3 = t >> 6;
        const int c1 = 4 * c3 + c1l;
        const float* xrow = x1s + c1 * 30;
        float a0 = xrow[p16];
        float a1 = hasb ? xrow[p16 + 16] : 0.f;

        // IN1 over 30 elems: butterfly within 16-lane channel group
        float s = a0 + a1, s2 = a0 * a0 + a1 * a1;
        #pragma unroll
        for (int m = 1; m <= 8; m <<= 1) {
            s  += __shfl_xor(s,  m);
            s2 += __shfl_xor(s2, m);
        }
        float mean = s * (1.f / 30.f);
        float var  = s2 * (1.f / 30.f) - mean * mean;
        float rstd = rsqrtf(var + 1e-5f);
        a0 = fmaxf((a0 - mean) * rstd, 0.f);
        a1 = fmaxf((a1 - mean) * rstd, 0.f);   // garbage if !hasb; masked

        // stage2: grouped conv 64->128
        const float w20 = w2[c1 * 2 + 0], w21 = w2[c1 * 2 + 1];
        const float b20 = b2[c1 * 2 + 0], b21 = b2[c1 * 2 + 1];
        float y00 = fmaf(a0, w20, b20), y01 = fmaf(a0, w21, b21);
        float y10 = fmaf(a1, w20, b20), y11 = fmaf(a1, w21, b21);

        // IN2 over 120 elems: butterfly within 32-lane half
        float u1 = y00 + y01 + (hasb ? (y10 + y11) : 0.f);
        float u2 = y00 * y00 + y01 * y01
                 + (hasb ? (y10 * y10 + y11 * y11) : 0.f);
        #pragma unroll
        for (int m = 1; m <= 16; m <<= 1) {
            u1 += __shfl_xor(u1, m);
            u2 += __shfl_xor(u2, m);
        }
        mean = u1 * (1.f / 120.f);
        var  = u2 * (1.f / 120.f) - mean * mean;
        rstd = rsqrtf(var + 1e-5f);
        y00 = fmaxf((y00 - mean) * rstd, 0.f);
        y01 = fmaxf((y01 - mean) * rstd, 0.f);
        y10 = fmaxf((y10 - mean) * rstd, 0.f);
        y11 = fmaxf((y11 - mean) * rstd, 0.f);

        // stage3: grouped conv 32->64
        const int c2 = c1 >> 1;
        const float w30 = w3[c2 * 2 + 0], w31 = w3[c2 * 2 + 1];
        const float b30 = b3[c2 * 2 + 0], b31 = b3[c2 * 2 + 1];
        float z000 = fmaf(y00, w30, b30), z001 = fmaf(y00, w31, b31);
        float z010 = fmaf(y01, w30, b30), z011 = fmaf(y01, w31, b31);
        float z100 = fmaf(y10, w30, b30), z101 = fmaf(y10, w31, b31);
        float z110 = fmaf(y11, w30, b30), z111 = fmaf(y11, w31, b31);

        // IN3 over 480 elems: full-wave butterfly
        float v1 = z000 + z001 + z010 + z011
                 + (hasb ? (z100 + z101 + z110 + z111) : 0.f);
        float v2 = z000 * z000 + z001 * z001 + z010 * z010 + z011 * z011
                 + (hasb ? (z100 * z100 + z101 * z101
                          + z110 * z110 + z111 * z111) : 0.f);
        #pragma unroll
        for (int m = 1; m <= 32; m <<= 1) {
            v1 += __shfl_xor(v1, m);
            v2 += __shfl_xor(v2, m);
        }
        mean = v1 * (1.f / 480.f);
        var  = v2 * (1.f / 480.f) - mean * mean;
        rstd = rsqrtf(var + 1e-5f);

        // normalize+relu -> h3; accumulate relu'd sums for IN4 stats
        // p(global in 480) = ((c2&1)*2 + j2)*120 + ((c1&1)*2 + j1)*30 + p1
        const int qb0 = (c1l >> 1) * 240;
        const int pb0 = (c1l & 1) * 60;
        float* hw = h3 + c3 * 480;
        float s4 = 0.f, q4 = 0.f;
        {
            float v;
            v = fmaxf((z000 - mean) * rstd, 0.f); hw[qb0 +       pb0 +      p16] = v; s4 += v; q4 += v * v;
            v = fmaxf((z001 - mean) * rstd, 0.f); hw[qb0 + 120 + pb0 +      p16] = v; s4 += v; q4 += v * v;
            v = fmaxf((z010 - mean) * rstd, 0.f); hw[qb0 +       pb0 + 30 + p16] = v; s4 += v; q4 += v * v;
            v = fmaxf((z011 - mean) * rstd, 0.f); hw[qb0 + 120 + pb0 + 30 + p16] = v; s4 += v; q4 += v * v;
            if (hasb) {
                v = fmaxf((z100 - mean) * rstd, 0.f); hw[qb0 +       pb0 +      p16 + 16] = v; s4 += v; q4 += v * v;
                v = fmaxf((z101 - mean) * rstd, 0.f); hw[qb0 + 120 + pb0 +      p16 + 16] = v; s4 += v; q4 += v * v;
                v = fmaxf((z110 - mean) * rstd, 0.f); hw[qb0 +       pb0 + 30 + p16 + 16] = v; s4 += v; q4 += v * v;
                v = fmaxf((z111 - mean) * rstd, 0.f); hw[qb0 + 120 + pb0 + 30 + p16 + 16] = v; s4 += v; q4 += v * v;
            }
        }
        #pragma unroll
        for (int m = 1; m <= 32; m <<= 1) {
            s4 += __shfl_xor(s4, m);
            q4 += __shfl_xor(q4, m);
        }
        if (l == 0) {
            // stage4 IN stats analytically:
            // x4[c, j*480+p] = h3[c,p]*w4[c*4+j] + b4[c*4+j]
            float sum4 = 0.f, sq4 = 0.f;
            #pragma unroll
            for (int j = 0; j < 4; ++j) {
                float ww = w4[c3 * 4 + j], bb = b4[c3 * 4 + j];
                sum4 += ww * s4 + 480.f * bb;
                sq4  += ww * ww * q4 + 2.f * ww * bb * s4 + 480.f * bb * bb;
            }
            float m4 = sum4 * (1.f / 1920.f);
            float var4 = sq4 * (1.f / 1920.f) - m4 * m4;
            m4s[c3] = m4; r4s[c3] = rsqrtf(var4 + 1e-5f);
        }
    }
    __syncthreads();

    // per-point: stage4 apply + stage5 einsum + tanh + emit + mark pairs
    for (int p = t; p < NPT; p += 1024) {
        int j = p / 480;
        int pp = p - j * 480;
        float a0e = b5[0], a1e = b5[1], a2e = b5[2];
        #pragma unroll
        for (int c = 0; c < 16; ++c) {
            float xv = h3[c * 480 + pp];
            float x4 = fmaf(xv, w4[c * 4 + j], b4[c * 4 + j]);
            float h  = fmaxf((x4 - m4s[c]) * r4s[c], 0.f);
            a0e = fmaf(w5[c],      h, a0e);
            a1e = fmaf(w5[16 + c], h, a1e);
            a2e = fmaf(w5[32 + c], h, a2e);
        }
        float px = tanhf(a0e) * 64.f + 63.5f;
        float py = tanhf(a1e) * 64.f + 63.5f;
        float pz = tanhf(a2e) * 64.f + 63.5f;
        float val = 1.f / (1.f + expf(-qval[p]));

        float4 pv; pv.x = px; pv.y = py; pv.z = pz; pv.w = val;
        pts[b * NPT + p] = pv;

        int x0 = (int)floorf(px), y0 = (int)floorf(py), z0 = (int)floorf(pz);
        int xlo = max(0, x0 - 3), xhi = min(127, x0 + 4);
        int ylo = max(0, y0 - 3), yhi = min(127, y0 + 4);
        int zlo = max(0, z0 - 3), zhi = min(127, z0 + 4);
        if (xlo > xhi || ylo > yhi || zlo > zhi) continue;
        int pxl = xlo >> 4, pxh = xhi >> 4;   // x-pair index
        int tyl = ylo >> 3, tyh = yhi >> 3;
        int tzl = zlo >> 3, tzh = zhi >> 3;
        for (int tz = tzl; tz <= tzh; ++tz)
            for (int ty = tyl; ty <= tyh; ++ty)
                for (int px2 = pxl; px2 <= pxh; ++px2)
                    lflags[(tz * 16 + ty) * 8 + px2] = 1;
    }
    __syncthreads();

    // compact this batch's active pairs into the global list
    for (int u = t; u < 2048; u += 1024) {
        if (lflags[u]) {
            int pos = atomicAdd(count, 1);
            list[pos] = (b << 11) | u;
        }
    }
}

// ---------------------------------------------------------------------------
// Tile kernel: 256 threads / 34.5 KB LDS -> 4 blocks/CU (same 16 waves/CU as
// the 512-thread version, but 2x independent tiles in flight and barriers
// sync 4 waves instead of 8). Grid-stride over the compacted active list.
// Splat -> in-place register-rolling z/y/x smooth -> divide -> store 16x8x8.
// In-place safety: output index g only overwrites input g, which no later
// output of that column reads; columns are thread-private.
// ---------------------------------------------------------------------------
__global__ __launch_bounds__(256, 4)
void tile_persist(const float4* __restrict__ pts, const int* __restrict__ count,
                  const int* __restrict__ list, float* __restrict__ out)
{
    __shared__ float2 raw[4312];   // 34,496 B

    const int cnt = *count;
    const int t = threadIdx.x;

    for (int idx = blockIdx.x; idx < cnt; idx += gridDim.x) {
        const int code = list[idx];
        const int pair = code & 7;
        const int ty   = (code >> 3) & 15;
        const int tz   = (code >> 7) & 15;
        const int b    = code >> 11;
        const int Tx = pair * 16, Ty = ty * 8, Tz = tz * 8;

        float* ob = out + (((size_t)(b * NVOX + Tz) * NVOX + Ty) * NVOX + Tx);

        {   // zero the LDS tile (float4 fill)
            float4* rz = (float4*)raw;
            for (int u = t; u < 2156; u += 256) rz[u] = make_float4(0.f, 0.f, 0.f, 0.f);
        }
        __syncthreads();

        // scatter this batch's points (raw covers [T-3, T+{19,11,11}))
        const float4* pb = pts + b * NPT;
        for (int p = t; p < NPT; p += 256) {
            float4 pt = pb[p];
            float x0f = floorf(pt.x), y0f = floorf(pt.y), z0f = floorf(pt.z);
            int x0 = (int)x0f, y0 = (int)y0f, z0 = (int)z0f;
            int lx0 = x0 - Tx + 3, ly0 = y0 - Ty + 3, lz0 = z0 - Tz + 3;
            if (lx0 + 1 < 0 || lx0 > 21 || ly0 + 1 < 0 || ly0 > 13 ||
                lz0 + 1 < 0 || lz0 > 13) continue;
            float fx = pt.x - x0f, fy = pt.y - y0f, fz = pt.z - z0f;
            float val = pt.w;
            #pragma unroll
            for (int dz = 0; dz < 2; ++dz) {
                int zi = z0 + dz, lz = lz0 + dz;
                if ((unsigned)zi >= 128u || (unsigned)lz >= 14u) continue;
                float wz = dz ? fz : 1.f - fz;
                #pragma unroll
                for (int dy = 0; dy < 2; ++dy) {
                    int yi = y0 + dy, ly = ly0 + dy;
                    if ((unsigned)yi >= 128u || (unsigned)ly >= 14u) continue;
                    float wy = dy ? fy : 1.f - fy;
                    #pragma unroll
                    for (int dx = 0; dx < 2; ++dx) {
                        int xi = x0 + dx, lx = lx0 + dx;
                        if ((unsigned)xi >= 128u || (unsigned)lx >= 22u) continue;
                        float w = (dx ? fx : 1.f - fx) * wy * wz;
                        float2* cell = &raw[(lz * 14 + ly) * 22 + lx];
                        atomicAdd(&cell->x, w * val);
                        atomicAdd(&cell->y, w);
                    }
                }
            }
        }
        __syncthreads();

        // z-pass IN PLACE: columns (ly,lx), stride 308; 2 per thread
        for (int c = t; c < 308; c += 256) {
            float2 w0 = raw[c],            w1_ = raw[c + 308],
                   w2_ = raw[c + 2 * 308], w3_ = raw[c + 3 * 308],
                   w4_ = raw[c + 4 * 308], w5_ = raw[c + 5 * 308],
                   w6_ = raw[c + 6 * 308];
            #pragma unroll
            for (int z = 0; z < 8; ++z) {
                float cm1, c0, cp1; coef(Tz + z, cm1, c0, cp1);
                float sx = (w0.x + w6_.x) + 3.f * (w1_.x + w5_.x)
                         + cm1 * w2_.x + c0 * w3_.x + cp1 * w4_.x;
                float sy = (w0.y + w6_.y) + 3.f * (w1_.y + w5_.y)
                         + cm1 * w2_.y + c0 * w3_.y + cp1 * w4_.y;
                float2 nxt = raw[c + ((z < 7) ? z + 7 : 7) * 308];
                raw[c + z * 308] = f2(sx * (1.f / 27.f), sy * (1.f / 27.f));
                w0 = w1_; w1_ = w2_; w2_ = w3_; w3_ = w4_; w4_ = w5_; w5_ = w6_; w6_ = nxt;
            }
        }
        __syncthreads();

        // y-pass IN PLACE: columns (z,lx), z<8, stride 22
        if (t < 176) {
            int z = t / 22, lx = t - z * 22;
            float2* base = &raw[z * 308 + lx];
            float2 w0 = base[0],       w1_ = base[22],
                   w2_ = base[2 * 22], w3_ = base[3 * 22],
                   w4_ = base[4 * 22], w5_ = base[5 * 22],
                   w6_ = base[6 * 22];
            #pragma unroll
            for (int y = 0; y < 8; ++y) {
                float cm1, c0, cp1; coef(Ty + y, cm1, c0, cp1);
                float sx = (w0.x + w6_.x) + 3.f * (w1_.x + w5_.x)
                         + cm1 * w2_.x + c0 * w3_.x + cp1 * w4_.x;
                float sy = (w0.y + w6_.y) + 3.f * (w1_.y + w5_.y)
                         + cm1 * w2_.y + c0 * w3_.y + cp1 * w4_.y;
                float2 nxt = base[((y < 7) ? y + 7 : 7) * 22];
                base[y * 22] = f2(sx * (1.f / 27.f), sy * (1.f / 27.f));
                w0 = w1_; w1_ = w2_; w2_ = w3_; w3_ = w4_; w4_ = w5_; w5_ = w6_; w6_ = nxt;
            }
        }
        __syncthreads();

        // x-pass + division: 2 threads per (z,y) row, 8 outputs each
        if (t < 128) {
            int row = t >> 1, hx = t & 1;
            int z = row >> 3, y = row & 7;
            const float2* a = &raw[z * 308 + y * 22 + hx * 8];
            float2 w0 = a[0], w1_ = a[1], w2_ = a[2], w3_ = a[3],
                   w4_ = a[4], w5_ = a[5], w6_ = a[6];
            float res[8];
            #pragma unroll
            for (int i = 0; i < 8; ++i) {
                int x = hx * 8 + i;
                float cm1, c0, cp1; coef(Tx + x, cm1, c0, cp1);
                float sx = (w0.x + w6_.x) + 3.f * (w1_.x + w5_.x)
                         + cm1 * w2_.x + c0 * w3_.x + cp1 * w4_.x;
                float sy = (w0.y + w6_.y) + 3.f * (w1_.y + w5_.y)
                         + cm1 * w2_.y + c0 * w3_.y + cp1 * w4_.y;
                res[i] = (sx * (1.f / 27.f)) / (sy * (1.f / 27.f) + 0.001f);
                float2 nxt = a[(i < 7) ? i + 7 : 13];
                w0 = w1_; w1_ = w2_; w2_ = w3_; w3_ = w4_; w4_ = w5_; w5_ = w6_; w6_ = nxt;
            }
            float* orow = &ob[((size_t)z * NVOX + y) * NVOX + hx * 8];
            *(float4*)&orow[0] = make_float4(res[0], res[1], res[2], res[3]);
            *(float4*)&orow[4] = make_float4(res[4], res[5], res[6], res[7]);
        }
        __syncthreads();   // raw re-zeroed next iteration
    }
}

// ---------------------------------------------------------------------------
extern "C" void kernel_launch(void* const* d_in, const int* in_sizes, int n_in,
                              void* d_out, int out_size, void* d_ws, size_t ws_size,
                              hipStream_t stream)
{
    const float* q    = (const float*)d_in[0];
    const float* qval = (const float*)d_in[1];
    const float* w1   = (const float*)d_in[2];
    const float* b1   = (const float*)d_in[3];
    const float* w2   = (const float*)d_in[4];
    const float* b2   = (const float*)d_in[5];
    const float* w3   = (const float*)d_in[6];
    const float* b3   = (const float*)d_in[7];
    const float* w4   = (const float*)d_in[8];
    const float* b4   = (const float*)d_in[9];
    const float* w5   = (const float*)d_in[10];
    const float* b5   = (const float*)d_in[11];
    float* out = (float*)d_out;

    // ws layout:
    //   [0,       16)    count (+pad)
    //   [16,  131088)    list (32768 ints)
    //   [131088, 622608) pts  (1920*16 float4)
    int*    count = (int*)d_ws;
    int*    list  = (int*)((char*)d_ws + 16);
    float4* pts   = (float4*)((char*)d_ws + 131088);

    zero_out<<<4096, 256, 0, stream>>>((float4*)out, count);

    mega_tail<<<NB, 1024, 0, stream>>>(q, w1, b1, qval, w2, b2, w3, b3,
                                       w4, b4, w5, b5, pts, count, list);

    tile_persist<<<2048, 256, 0, stream>>>(pts, count, list, out);
}

// Round 11
// 219.592 us; speedup vs baseline: 4.7495x; 1.0332x over previous
//
#include <hip/hip_runtime.h>
#include <cstddef>

// Problem constants
#define NB 16
#define NVOX 128
#define NPT 1920

static __device__ __forceinline__ float2 f2(float a, float b) {
    float2 r; r.x = a; r.y = b; return r;
}

// Per-axis composed 7-tap coefficients (A^3 of zero-padded 3-tap average):
// interior [1,3,6,7,6,3,1]/27; boundary rows via cm1/c0/cp1 overrides.
__device__ __forceinline__ void coef(int g, float& cm1, float& c0, float& cp1)
{
    cm1 = (g == 1 || g == 127) ? 5.f : 6.f;
    c0  = (g == 0 || g == 127) ? 4.f : 7.f;
    cp1 = (g == 0 || g == 126) ? 5.f : 6.f;
}

// ---------------------------------------------------------------------------
// Fused tail + zero kernel, grid 512 x 1024 (R8-proven split, R10 tail body).
// Blocks 0-15: per-batch MLP tail + point gen + per-batch pair list.
// Blocks 16-511: zero the 134 MB output at full write BW, concurrently.
// Per-batch bcount/list are unconditionally overwritten -> no memset needed.
// Active tiles are overwritten later by tile_persist (kernel boundary
// orders the writes; no intra-kernel write-write sharing).
// ---------------------------------------------------------------------------
__global__ __launch_bounds__(1024)
void tail_zero_k(const float* __restrict__ q, const float* __restrict__ w1,
                 const float* __restrict__ b1, const float* __restrict__ qval,
                 const float* __restrict__ w2, const float* __restrict__ b2,
                 const float* __restrict__ w3, const float* __restrict__ b3,
                 const float* __restrict__ w4, const float* __restrict__ b4,
                 const float* __restrict__ w5, const float* __restrict__ b5,
                 float4* __restrict__ pts, int* __restrict__ bcount,
                 int* __restrict__ list, float4* __restrict__ out4)
{
    const int bid = blockIdx.x;
    const int t = threadIdx.x;

    if (bid >= NB) {
        // ---------------- zero phase (496 blocks x 1024 thr) ----------------
        const int stride = 496 * 1024;
        const int n4 = (NB * NVOX * NVOX * NVOX) / 4;
        for (int i = (bid - NB) * 1024 + t; i < n4; i += stride)
            out4[i] = make_float4(0.f, 0.f, 0.f, 0.f);
        return;
    }

    // ---------------- tail phase (16 blocks, R10-verified body) ----------------
    __shared__ float x1s[1920];          // stage1 output, flat (64,30)
    __shared__ float h3[7680];           // relu'd IN3; first 2048 double as qs
    __shared__ float m4s[16], r4s[16];
    __shared__ unsigned char lflags[2048];   // tz16 * ty16 * px8 pair flags
    __shared__ int lcount;

    const int b = bid;
    float* qs = h3;    // overlay: h3 not live until after stage1

    for (int u = t; u < 2048; u += 1024) {
        qs[u] = q[b * 2048 + u];
        lflags[u] = 0;
    }
    if (t == 0) lcount = 0;
    __syncthreads();

    // stage1: x1[(o,l)] = b1[o] + sum_i w1[o,i] * q[b, i*8+l]
    for (int u = t; u < 1920; u += 1024) {
        int o = u >> 3, l = u & 7;
        const float4* wr = (const float4*)(w1 + o * 256);
        float acc = 0.f;
        #pragma unroll 8
        for (int i4 = 0; i4 < 64; ++i4) {
            float4 w = wr[i4];
            int base = i4 * 32 + l;
            acc = fmaf(w.x, qs[base],      acc);
            acc = fmaf(w.y, qs[base + 8],  acc);
            acc = fmaf(w.z, qs[base + 16], acc);
            acc = fmaf(w.w, qs[base + 24], acc);
        }
        x1s[u] = b1[o] + acc;
    }
    __syncthreads();   // qs dead from here; h3 live

    // wave-per-channel chain: wave w == final channel c3
    const int l = t & 63;
    const int c1l = l >> 4;
    const int p16 = l & 15;
    const bool hasb = (p16 < 14);    // second element p16+16 < 30
    {
        const int c3 = t >> 6;
        const int c1 = 4 * c3 + c1l;
        const float* xrow = x1s + c1 * 30;
        float a0 = xrow[p16];
        float a1 = hasb ? xrow[p16 + 16] : 0.f;

        // IN1 over 30 elems: butterfly within 16-lane channel group
        float s = a0 + a1, s2 = a0 * a0 + a1 * a1;
        #pragma unroll
        for (int m = 1; m <= 8; m <<= 1) {
            s  += __shfl_xor(s,  m);
            s2 += __shfl_xor(s2, m);
        }
        float mean = s * (1.f / 30.f);
        float var  = s2 * (1.f / 30.f) - mean * mean;
        float rstd = rsqrtf(var + 1e-5f);
        a0 = fmaxf((a0 - mean) * rstd, 0.f);
        a1 = fmaxf((a1 - mean) * rstd, 0.f);   // garbage if !hasb; masked

        // stage2: grouped conv 64->128
        const float w20 = w2[c1 * 2 + 0], w21 = w2[c1 * 2 + 1];
        const float b20 = b2[c1 * 2 + 0], b21 = b2[c1 * 2 + 1];
        float y00 = fmaf(a0, w20, b20), y01 = fmaf(a0, w21, b21);
        float y10 = fmaf(a1, w20, b20), y11 = fmaf(a1, w21, b21);

        // IN2 over 120 elems: butterfly within 32-lane half
        float u1 = y00 + y01 + (hasb ? (y10 + y11) : 0.f);
        float u2 = y00 * y00 + y01 * y01
                 + (hasb ? (y10 * y10 + y11 * y11) : 0.f);
        #pragma unroll
        for (int m = 1; m <= 16; m <<= 1) {
            u1 += __shfl_xor(u1, m);
            u2 += __shfl_xor(u2, m);
        }
        mean = u1 * (1.f / 120.f);
        var  = u2 * (1.f / 120.f) - mean * mean;
        rstd = rsqrtf(var + 1e-5f);
        y00 = fmaxf((y00 - mean) * rstd, 0.f);
        y01 = fmaxf((y01 - mean) * rstd, 0.f);
        y10 = fmaxf((y10 - mean) * rstd, 0.f);
        y11 = fmaxf((y11 - mean) * rstd, 0.f);

        // stage3: grouped conv 32->64
        const int c2 = c1 >> 1;
        const float w30 = w3[c2 * 2 + 0], w31 = w3[c2 * 2 + 1];
        const float b30 = b3[c2 * 2 + 0], b31 = b3[c2 * 2 + 1];
        float z000 = fmaf(y00, w30, b30), z001 = fmaf(y00, w31, b31);
        float z010 = fmaf(y01, w30, b30), z011 = fmaf(y01, w31, b31);
        float z100 = fmaf(y10, w30, b30), z101 = fmaf(y10, w31, b31);
        float z110 = fmaf(y11, w30, b30), z111 = fmaf(y11, w31, b31);

        // IN3 over 480 elems: full-wave butterfly
        float v1 = z000 + z001 + z010 + z011
                 + (hasb ? (z100 + z101 + z110 + z111) : 0.f);
        float v2 = z000 * z000 + z001 * z001 + z010 * z010 + z011 * z011
                 + (hasb ? (z100 * z100 + z101 * z101
                          + z110 * z110 + z111 * z111) : 0.f);
        #pragma unroll
        for (int m = 1; m <= 32; m <<= 1) {
            v1 += __shfl_xor(v1, m);
            v2 += __shfl_xor(v2, m);
        }
        mean = v1 * (1.f / 480.f);
        var  = v2 * (1.f / 480.f) - mean * mean;
        rstd = rsqrtf(var + 1e-5f);

        // normalize+relu -> h3; accumulate relu'd sums for IN4 stats
        // p(global in 480) = ((c2&1)*2 + j2)*120 + ((c1&1)*2 + j1)*30 + p1
        const int qb0 = (c1l >> 1) * 240;
        const int pb0 = (c1l & 1) * 60;
        float* hw = h3 + c3 * 480;
        float s4 = 0.f, q4 = 0.f;
        {
            float v;
            v = fmaxf((z000 - mean) * rstd, 0.f); hw[qb0 +       pb0 +      p16] = v; s4 += v; q4 += v * v;
            v = fmaxf((z001 - mean) * rstd, 0.f); hw[qb0 + 120 + pb0 +      p16] = v; s4 += v; q4 += v * v;
            v = fmaxf((z010 - mean) * rstd, 0.f); hw[qb0 +       pb0 + 30 + p16] = v; s4 += v; q4 += v * v;
            v = fmaxf((z011 - mean) * rstd, 0.f); hw[qb0 + 120 + pb0 + 30 + p16] = v; s4 += v; q4 += v * v;
            if (hasb) {
                v = fmaxf((z100 - mean) * rstd, 0.f); hw[qb0 +       pb0 +      p16 + 16] = v; s4 += v; q4 += v * v;
                v = fmaxf((z101 - mean) * rstd, 0.f); hw[qb0 + 120 + pb0 +      p16 + 16] = v; s4 += v; q4 += v * v;
                v = fmaxf((z110 - mean) * rstd, 0.f); hw[qb0 +       pb0 + 30 + p16 + 16] = v; s4 += v; q4 += v * v;
                v = fmaxf((z111 - mean) * rstd, 0.f); hw[qb0 + 120 + pb0 + 30 + p16 + 16] = v; s4 += v; q4 += v * v;
            }
        }
        #pragma unroll
        for (int m = 1; m <= 32; m <<= 1) {
            s4 += __shfl_xor(s4, m);
            q4 += __shfl_xor(q4, m);
        }
        if (l == 0) {
            // stage4 IN stats analytically:
            // x4[c, j*480+p] = h3[c,p]*w4[c*4+j] + b4[c*4+j]
            float sum4 = 0.f, sq4 = 0.f;
            #pragma unroll
            for (int j = 0; j < 4; ++j) {
                float ww = w4[c3 * 4 + j], bb = b4[c3 * 4 + j];
                sum4 += ww * s4 + 480.f * bb;
                sq4  += ww * ww * q4 + 2.f * ww * bb * s4 + 480.f * bb * bb;
            }
            float m4 = sum4 * (1.f / 1920.f);
            float var4 = sq4 * (1.f / 1920.f) - m4 * m4;
            m4s[c3] = m4; r4s[c3] = rsqrtf(var4 + 1e-5f);
        }
    }
    __syncthreads();

    // per-point: stage4 apply + stage5 einsum + tanh + emit + mark pairs
    for (int p = t; p < NPT; p += 1024) {
        int j = p / 480;
        int pp = p - j * 480;
        float a0e = b5[0], a1e = b5[1], a2e = b5[2];
        #pragma unroll
        for (int c = 0; c < 16; ++c) {
            float xv = h3[c * 480 + pp];
            float x4 = fmaf(xv, w4[c * 4 + j], b4[c * 4 + j]);
            float h  = fmaxf((x4 - m4s[c]) * r4s[c], 0.f);
            a0e = fmaf(w5[c],      h, a0e);
            a1e = fmaf(w5[16 + c], h, a1e);
            a2e = fmaf(w5[32 + c], h, a2e);
        }
        float px = tanhf(a0e) * 64.f + 63.5f;
        float py = tanhf(a1e) * 64.f + 63.5f;
        float pz = tanhf(a2e) * 64.f + 63.5f;
        float val = 1.f / (1.f + expf(-qval[p]));

        float4 pv; pv.x = px; pv.y = py; pv.z = pz; pv.w = val;
        pts[b * NPT + p] = pv;

        int x0 = (int)floorf(px), y0 = (int)floorf(py), z0 = (int)floorf(pz);
        int xlo = max(0, x0 - 3), xhi = min(127, x0 + 4);
        int ylo = max(0, y0 - 3), yhi = min(127, y0 + 4);
        int zlo = max(0, z0 - 3), zhi = min(127, z0 + 4);
        if (xlo > xhi || ylo > yhi || zlo > zhi) continue;
        int pxl = xlo >> 4, pxh = xhi >> 4;   // x-pair index
        int tyl = ylo >> 3, tyh = yhi >> 3;
        int tzl = zlo >> 3, tzh = zhi >> 3;
        for (int tz = tzl; tz <= tzh; ++tz)
            for (int ty = tyl; ty <= tyh; ++ty)
                for (int px2 = pxl; px2 <= pxh; ++px2)
                    lflags[(tz * 16 + ty) * 8 + px2] = 1;
    }
    __syncthreads();

    // compact this batch's active pairs into its list segment
    for (int u = t; u < 2048; u += 1024) {
        if (lflags[u]) {
            int pos = atomicAdd(&lcount, 1);
            list[b * 2048 + pos] = (b << 11) | u;
        }
    }
    __syncthreads();
    if (t == 0) bcount[b] = lcount;
}

// ---------------------------------------------------------------------------
// Tile kernel (R10-verified body, R8-verified prefix decode): 256 threads /
// 34.5 KB LDS -> 4 blocks/CU, grid-stride over the concatenated per-batch
// lists. Splat -> in-place register-rolling z/y/x smooth -> divide -> store.
// In-place safety: output index g only overwrites input g, which no later
// output of that column reads; columns are thread-private.
// ---------------------------------------------------------------------------
__global__ __launch_bounds__(256, 4)
void tile_persist(const float4* __restrict__ pts, const int* __restrict__ bcount,
                  const int* __restrict__ list, float* __restrict__ out)
{
    __shared__ float2 raw[4312];   // 34,496 B
    __shared__ int pf[17];

    const int t = threadIdx.x;
    if (t < 16) pf[t + 1] = bcount[t];
    if (t == 0) pf[0] = 0;
    __syncthreads();
    if (t == 0) {
        int s = 0;
        #pragma unroll
        for (int i = 1; i <= 16; ++i) { s += pf[i]; pf[i] = s; }
    }
    __syncthreads();
    const int total = pf[16];

    for (int idx = blockIdx.x; idx < total; idx += gridDim.x) {
        int bb = 0;
        #pragma unroll 1
        for (; bb < 15; ++bb) if (idx < pf[bb + 1]) break;
        const int code = list[bb * 2048 + (idx - pf[bb])];
        const int pair = code & 7;
        const int ty   = (code >> 3) & 15;
        const int tz   = (code >> 7) & 15;
        const int b    = code >> 11;
        const int Tx = pair * 16, Ty = ty * 8, Tz = tz * 8;

        float* ob = out + (((size_t)(b * NVOX + Tz) * NVOX + Ty) * NVOX + Tx);

        {   // zero the LDS tile (float4 fill)
            float4* rz = (float4*)raw;
            for (int u = t; u < 2156; u += 256) rz[u] = make_float4(0.f, 0.f, 0.f, 0.f);
        }
        __syncthreads();

        // scatter this batch's points (raw covers [T-3, T+{19,11,11}))
        const float4* pb = pts + b * NPT;
        for (int p = t; p < NPT; p += 256) {
            float4 pt = pb[p];
            float x0f = floorf(pt.x), y0f = floorf(pt.y), z0f = floorf(pt.z);
            int x0 = (int)x0f, y0 = (int)y0f, z0 = (int)z0f;
            int lx0 = x0 - Tx + 3, ly0 = y0 - Ty + 3, lz0 = z0 - Tz + 3;
            if (lx0 + 1 < 0 || lx0 > 21 || ly0 + 1 < 0 || ly0 > 13 ||
                lz0 + 1 < 0 || lz0 > 13) continue;
            float fx = pt.x - x0f, fy = pt.y - y0f, fz = pt.z - z0f;
            float val = pt.w;
            #pragma unroll
            for (int dz = 0; dz < 2; ++dz) {
                int zi = z0 + dz, lz = lz0 + dz;
                if ((unsigned)zi >= 128u || (unsigned)lz >= 14u) continue;
                float wz = dz ? fz : 1.f - fz;
                #pragma unroll
                for (int dy = 0; dy < 2; ++dy) {
                    int yi = y0 + dy, ly = ly0 + dy;
                    if ((unsigned)yi >= 128u || (unsigned)ly >= 14u) continue;
                    float wy = dy ? fy : 1.f - fy;
                    #pragma unroll
                    for (int dx = 0; dx < 2; ++dx) {
                        int xi = x0 + dx, lx = lx0 + dx;
                        if ((unsigned)xi >= 128u || (unsigned)lx >= 22u) continue;
                        float w = (dx ? fx : 1.f - fx) * wy * wz;
                        float2* cell = &raw[(lz * 14 + ly) * 22 + lx];
                        atomicAdd(&cell->x, w * val);
                        atomicAdd(&cell->y, w);
                    }
                }
            }
        }
        __syncthreads();

        // z-pass IN PLACE: columns (ly,lx), stride 308; 2 per thread
        for (int c = t; c < 308; c += 256) {
            float2 w0 = raw[c],            w1_ = raw[c + 308],
                   w2_ = raw[c + 2 * 308], w3_ = raw[c + 3 * 308],
                   w4_ = raw[c + 4 * 308], w5_ = raw[c + 5 * 308],
                   w6_ = raw[c + 6 * 308];
            #pragma unroll
            for (int z = 0; z < 8; ++z) {
                float cm1, c0, cp1; coef(Tz + z, cm1, c0, cp1);
                float sx = (w0.x + w6_.x) + 3.f * (w1_.x + w5_.x)
                         + cm1 * w2_.x + c0 * w3_.x + cp1 * w4_.x;
                float sy = (w0.y + w6_.y) + 3.f * (w1_.y + w5_.y)
                         + cm1 * w2_.y + c0 * w3_.y + cp1 * w4_.y;
                float2 nxt = raw[c + ((z < 7) ? z + 7 : 7) * 308];
                raw[c + z * 308] = f2(sx * (1.f / 27.f), sy * (1.f / 27.f));
                w0 = w1_; w1_ = w2_; w2_ = w3_; w3_ = w4_; w4_ = w5_; w5_ = w6_; w6_ = nxt;
            }
        }
        __syncthreads();

        // y-pass IN PLACE: columns (z,lx), z<8, stride 22
        if (t < 176) {
            int z = t / 22, lx = t - z * 22;
            float2* base = &raw[z * 308 + lx];
            float2 w0 = base[0],       w1_ = base[22],
                   w2_ = base[2 * 22], w3_ = base[3 * 22],
                   w4_ = base[4 * 22], w5_ = base[5 * 22],
                   w6_ = base[6 * 22];
            #pragma unroll
            for (int y = 0; y < 8; ++y) {
                float cm1, c0, cp1; coef(Ty + y, cm1, c0, cp1);
                float sx = (w0.x + w6_.x) + 3.f * (w1_.x + w5_.x)
                         + cm1 * w2_.x + c0 * w3_.x + cp1 * w4_.x;
                float sy = (w0.y + w6_.y) + 3.f * (w1_.y + w5_.y)
                         + cm1 * w2_.y + c0 * w3_.y + cp1 * w4_.y;
                float2 nxt = base[((y < 7) ? y + 7 : 7) * 22];
                base[y * 22] = f2(sx * (1.f / 27.f), sy * (1.f / 27.f));
                w0 = w1_; w1_ = w2_; w2_ = w3_; w3_ = w4_; w4_ = w5_; w5_ = w6_; w6_ = nxt;
            }
        }
        __syncthreads();

        // x-pass + division: 2 threads per (z,y) row, 8 outputs each
        if (t < 128) {
            int row = t >> 1, hx = t & 1;
            int z = row >> 3, y = row & 7;
            const float2* a = &raw[z * 308 + y * 22 + hx * 8];
            float2 w0 = a[0], w1_ = a[1], w2_ = a[2], w3_ = a[3],
                   w4_ = a[4], w5_ = a[5], w6_ = a[6];
            float res[8];
            #pragma unroll
            for (int i = 0; i < 8; ++i) {
                int x = hx * 8 + i;
                float cm1, c0, cp1; coef(Tx + x, cm1, c0, cp1);
                float sx = (w0.x + w6_.x) + 3.f * (w1_.x + w5_.x)
                         + cm1 * w2_.x + c0 * w3_.x + cp1 * w4_.x;
                float sy = (w0.y + w6_.y) + 3.f * (w1_.y + w5_.y)
                         + cm1 * w2_.y + c0 * w3_.y + cp1 * w4_.y;
                res[i] = (sx * (1.f / 27.f)) / (sy * (1.f / 27.f) + 0.001f);
                float2 nxt = a[(i < 7) ? i + 7 : 13];
                w0 = w1_; w1_ = w2_; w2_ = w3_; w3_ = w4_; w4_ = w5_; w5_ = w6_; w6_ = nxt;
            }
            float* orow = &ob[((size_t)z * NVOX + y) * NVOX + hx * 8];
            *(float4*)&orow[0] = make_float4(res[0], res[1], res[2], res[3]);
            *(float4*)&orow[4] = make_float4(res[4], res[5], res[6], res[7]);
        }
        __syncthreads();   // raw re-zeroed next iteration
    }
}

// ---------------------------------------------------------------------------
extern "C" void kernel_launch(void* const* d_in, const int* in_sizes, int n_in,
                              void* d_out, int out_size, void* d_ws, size_t ws_size,
                              hipStream_t stream)
{
    const float* q    = (const float*)d_in[0];
    const float* qval = (const float*)d_in[1];
    const float* w1   = (const float*)d_in[2];
    const float* b1   = (const float*)d_in[3];
    const float* w2   = (const float*)d_in[4];
    const float* b2   = (const float*)d_in[5];
    const float* w3   = (const float*)d_in[6];
    const float* b3   = (const float*)d_in[7];
    const float* w4   = (const float*)d_in[8];
    const float* b4   = (const float*)d_in[9];
    const float* w5   = (const float*)d_in[10];
    const float* b5   = (const float*)d_in[11];
    float* out = (float*)d_out;

    // ws layout:
    //   [0,       64)    bcount (16 ints, padded)
    //   [64,  131136)    list (16 x 2048 ints)
    //   [131136, 622656) pts  (16 x 1920 float4)
    int*    bcount = (int*)d_ws;
    int*    list   = (int*)((char*)d_ws + 64);
    float4* pts    = (float4*)((char*)d_ws + 131136);

    tail_zero_k<<<512, 1024, 0, stream>>>(q, w1, b1, qval, w2, b2, w3, b3,
                                          w4, b4, w5, b5, pts, bcount, list,
                                          (float4*)out);

    tile_persist<<<2048, 256, 0, stream>>>(pts, bcount, list, out);
}

// Round 12
// 218.929 us; speedup vs baseline: 4.7639x; 1.0030x over previous
//
#include <hip/hip_runtime.h>
#include <cstddef>

// Problem constants
#define NB 16
#define NVOX 128
#define NPT 1920

static __device__ __forceinline__ float2 f2(float a, float b) {
    float2 r; r.x = a; r.y = b; return r;
}

// Per-axis composed 7-tap coefficients (A^3 of zero-padded 3-tap average):
// interior [1,3,6,7,6,3,1]/27; boundary rows via cm1/c0/cp1 overrides.
__device__ __forceinline__ void coef(int g, float& cm1, float& c0, float& cp1)
{
    cm1 = (g == 1 || g == 127) ? 5.f : 6.f;
    c0  = (g == 0 || g == 127) ? 4.f : 7.f;
    cp1 = (g == 0 || g == 126) ? 5.f : 6.f;
}

// ---------------------------------------------------------------------------
// Fused tail + zero kernel (R11-verified, byte-identical), grid 512 x 1024.
// Blocks 0-15: per-batch MLP tail + point gen + per-batch pair list.
// Blocks 16-511: zero the 134 MB output at full write BW, concurrently.
// ---------------------------------------------------------------------------
__global__ __launch_bounds__(1024)
void tail_zero_k(const float* __restrict__ q, const float* __restrict__ w1,
                 const float* __restrict__ b1, const float* __restrict__ qval,
                 const float* __restrict__ w2, const float* __restrict__ b2,
                 const float* __restrict__ w3, const float* __restrict__ b3,
                 const float* __restrict__ w4, const float* __restrict__ b4,
                 const float* __restrict__ w5, const float* __restrict__ b5,
                 float4* __restrict__ pts, int* __restrict__ bcount,
                 int* __restrict__ list, float4* __restrict__ out4)
{
    const int bid = blockIdx.x;
    const int t = threadIdx.x;

    if (bid >= NB) {
        // ---------------- zero phase (496 blocks x 1024 thr) ----------------
        const int stride = 496 * 1024;
        const int n4 = (NB * NVOX * NVOX * NVOX) / 4;
        for (int i = (bid - NB) * 1024 + t; i < n4; i += stride)
            out4[i] = make_float4(0.f, 0.f, 0.f, 0.f);
        return;
    }

    // ---------------- tail phase (16 blocks, R10-verified body) ----------------
    __shared__ float x1s[1920];          // stage1 output, flat (64,30)
    __shared__ float h3[7680];           // relu'd IN3; first 2048 double as qs
    __shared__ float m4s[16], r4s[16];
    __shared__ unsigned char lflags[2048];   // tz16 * ty16 * px8 pair flags
    __shared__ int lcount;

    const int b = bid;
    float* qs = h3;    // overlay: h3 not live until after stage1

    for (int u = t; u < 2048; u += 1024) {
        qs[u] = q[b * 2048 + u];
        lflags[u] = 0;
    }
    if (t == 0) lcount = 0;
    __syncthreads();

    // stage1: x1[(o,l)] = b1[o] + sum_i w1[o,i] * q[b, i*8+l]
    for (int u = t; u < 1920; u += 1024) {
        int o = u >> 3, l = u & 7;
        const float4* wr = (const float4*)(w1 + o * 256);
        float acc = 0.f;
        #pragma unroll 8
        for (int i4 = 0; i4 < 64; ++i4) {
            float4 w = wr[i4];
            int base = i4 * 32 + l;
            acc = fmaf(w.x, qs[base],      acc);
            acc = fmaf(w.y, qs[base + 8],  acc);
            acc = fmaf(w.z, qs[base + 16], acc);
            acc = fmaf(w.w, qs[base + 24], acc);
        }
        x1s[u] = b1[o] + acc;
    }
    __syncthreads();   // qs dead from here; h3 live

    // wave-per-channel chain: wave w == final channel c3
    const int l = t & 63;
    const int c1l = l >> 4;
    const int p16 = l & 15;
    const bool hasb = (p16 < 14);    // second element p16+16 < 30
    {
        const int c3 = t >> 6;
        const int c1 = 4 * c3 + c1l;
        const float* xrow = x1s + c1 * 30;
        float a0 = xrow[p16];
        float a1 = hasb ? xrow[p16 + 16] : 0.f;

        // IN1 over 30 elems: butterfly within 16-lane channel group
        float s = a0 + a1, s2 = a0 * a0 + a1 * a1;
        #pragma unroll
        for (int m = 1; m <= 8; m <<= 1) {
            s  += __shfl_xor(s,  m);
            s2 += __shfl_xor(s2, m);
        }
        float mean = s * (1.f / 30.f);
        float var  = s2 * (1.f / 30.f) - mean * mean;
        float rstd = rsqrtf(var + 1e-5f);
        a0 = fmaxf((a0 - mean) * rstd, 0.f);
        a1 = fmaxf((a1 - mean) * rstd, 0.f);   // garbage if !hasb; masked

        // stage2: grouped conv 64->128
        const float w20 = w2[c1 * 2 + 0], w21 = w2[c1 * 2 + 1];
        const float b20 = b2[c1 * 2 + 0], b21 = b2[c1 * 2 + 1];
        float y00 = fmaf(a0, w20, b20), y01 = fmaf(a0, w21, b21);
        float y10 = fmaf(a1, w20, b20), y11 = fmaf(a1, w21, b21);

        // IN2 over 120 elems: butterfly within 32-lane half
        float u1 = y00 + y01 + (hasb ? (y10 + y11) : 0.f);
        float u2 = y00 * y00 + y01 * y01
                 + (hasb ? (y10 * y10 + y11 * y11) : 0.f);
        #pragma unroll
        for (int m = 1; m <= 16; m <<= 1) {
            u1 += __shfl_xor(u1, m);
            u2 += __shfl_xor(u2, m);
        }
        mean = u1 * (1.f / 120.f);
        var  = u2 * (1.f / 120.f) - mean * mean;
        rstd = rsqrtf(var + 1e-5f);
        y00 = fmaxf((y00 - mean) * rstd, 0.f);
        y01 = fmaxf((y01 - mean) * rstd, 0.f);
        y10 = fmaxf((y10 - mean) * rstd, 0.f);
        y11 = fmaxf((y11 - mean) * rstd, 0.f);

        // stage3: grouped conv 32->64
        const int c2 = c1 >> 1;
        const float w30 = w3[c2 * 2 + 0], w31 = w3[c2 * 2 + 1];
        const float b30 = b3[c2 * 2 + 0], b31 = b3[c2 * 2 + 1];
        float z000 = fmaf(y00, w30, b30), z001 = fmaf(y00, w31, b31);
        float z010 = fmaf(y01, w30, b30), z011 = fmaf(y01, w31, b31);
        float z100 = fmaf(y10, w30, b30), z101 = fmaf(y10, w31, b31);
        float z110 = fmaf(y11, w30, b30), z111 = fmaf(y11, w31, b31);

        // IN3 over 480 elems: full-wave butterfly
        float v1 = z000 + z001 + z010 + z011
                 + (hasb ? (z100 + z101 + z110 + z111) : 0.f);
        float v2 = z000 * z000 + z001 * z001 + z010 * z010 + z011 * z011
                 + (hasb ? (z100 * z100 + z101 * z101
                          + z110 * z110 + z111 * z111) : 0.f);
        #pragma unroll
        for (int m = 1; m <= 32; m <<= 1) {
            v1 += __shfl_xor(v1, m);
            v2 += __shfl_xor(v2, m);
        }
        mean = v1 * (1.f / 480.f);
        var  = v2 * (1.f / 480.f) - mean * mean;
        rstd = rsqrtf(var + 1e-5f);

        // normalize+relu -> h3; accumulate relu'd sums for IN4 stats
        // p(global in 480) = ((c2&1)*2 + j2)*120 + ((c1&1)*2 + j1)*30 + p1
        const int qb0 = (c1l >> 1) * 240;
        const int pb0 = (c1l & 1) * 60;
        float* hw = h3 + c3 * 480;
        float s4 = 0.f, q4 = 0.f;
        {
            float v;
            v = fmaxf((z000 - mean) * rstd, 0.f); hw[qb0 +       pb0 +      p16] = v; s4 += v; q4 += v * v;
            v = fmaxf((z001 - mean) * rstd, 0.f); hw[qb0 + 120 + pb0 +      p16] = v; s4 += v; q4 += v * v;
            v = fmaxf((z010 - mean) * rstd, 0.f); hw[qb0 +       pb0 + 30 + p16] = v; s4 += v; q4 += v * v;
            v = fmaxf((z011 - mean) * rstd, 0.f); hw[qb0 + 120 + pb0 + 30 + p16] = v; s4 += v; q4 += v * v;
            if (hasb) {
                v = fmaxf((z100 - mean) * rstd, 0.f); hw[qb0 +       pb0 +      p16 + 16] = v; s4 += v; q4 += v * v;
                v = fmaxf((z101 - mean) * rstd, 0.f); hw[qb0 + 120 + pb0 +      p16 + 16] = v; s4 += v; q4 += v * v;
                v = fmaxf((z110 - mean) * rstd, 0.f); hw[qb0 +       pb0 + 30 + p16 + 16] = v; s4 += v; q4 += v * v;
                v = fmaxf((z111 - mean) * rstd, 0.f); hw[qb0 + 120 + pb0 + 30 + p16 + 16] = v; s4 += v; q4 += v * v;
            }
        }
        #pragma unroll
        for (int m = 1; m <= 32; m <<= 1) {
            s4 += __shfl_xor(s4, m);
            q4 += __shfl_xor(q4, m);
        }
        if (l == 0) {
            // stage4 IN stats analytically:
            // x4[c, j*480+p] = h3[c,p]*w4[c*4+j] + b4[c*4+j]
            float sum4 = 0.f, sq4 = 0.f;
            #pragma unroll
            for (int j = 0; j < 4; ++j) {
                float ww = w4[c3 * 4 + j], bb = b4[c3 * 4 + j];
                sum4 += ww * s4 + 480.f * bb;
                sq4  += ww * ww * q4 + 2.f * ww * bb * s4 + 480.f * bb * bb;
            }
            float m4 = sum4 * (1.f / 1920.f);
            float var4 = sq4 * (1.f / 1920.f) - m4 * m4;
            m4s[c3] = m4; r4s[c3] = rsqrtf(var4 + 1e-5f);
        }
    }
    __syncthreads();

    // per-point: stage4 apply + stage5 einsum + tanh + emit + mark pairs
    for (int p = t; p < NPT; p += 1024) {
        int j = p / 480;
        int pp = p - j * 480;
        float a0e = b5[0], a1e = b5[1], a2e = b5[2];
        #pragma unroll
        for (int c = 0; c < 16; ++c) {
            float xv = h3[c * 480 + pp];
            float x4 = fmaf(xv, w4[c * 4 + j], b4[c * 4 + j]);
            float h  = fmaxf((x4 - m4s[c]) * r4s[c], 0.f);
            a0e = fmaf(w5[c],      h, a0e);
            a1e = fmaf(w5[16 + c], h, a1e);
            a2e = fmaf(w5[32 + c], h, a2e);
        }
        float px = tanhf(a0e) * 64.f + 63.5f;
        float py = tanhf(a1e) * 64.f + 63.5f;
        float pz = tanhf(a2e) * 64.f + 63.5f;
        float val = 1.f / (1.f + expf(-qval[p]));

        float4 pv; pv.x = px; pv.y = py; pv.z = pz; pv.w = val;
        pts[b * NPT + p] = pv;

        int x0 = (int)floorf(px), y0 = (int)floorf(py), z0 = (int)floorf(pz);
        int xlo = max(0, x0 - 3), xhi = min(127, x0 + 4);
        int ylo = max(0, y0 - 3), yhi = min(127, y0 + 4);
        int zlo = max(0, z0 - 3), zhi = min(127, z0 + 4);
        if (xlo > xhi || ylo > yhi || zlo > zhi) continue;
        int pxl = xlo >> 4, pxh = xhi >> 4;   // x-pair index
        int tyl = ylo >> 3, tyh = yhi >> 3;
        int tzl = zlo >> 3, tzh = zhi >> 3;
        for (int tz = tzl; tz <= tzh; ++tz)
            for (int ty = tyl; ty <= tyh; ++ty)
                for (int px2 = pxl; px2 <= pxh; ++px2)
                    lflags[(tz * 16 + ty) * 8 + px2] = 1;
    }
    __syncthreads();

    // compact this batch's active pairs into its list segment
    for (int u = t; u < 2048; u += 1024) {
        if (lflags[u]) {
            int pos = atomicAdd(&lcount, 1);
            list[b * 2048 + pos] = (b << 11) | u;
        }
    }
    __syncthreads();
    if (t == 0) bcount[b] = lcount;
}

// ---------------------------------------------------------------------------
// Tile kernel: 256 threads / 34.5 KB LDS -> 4 blocks/CU, grid-stride over
// the concatenated per-batch lists. NEW: smoothing passes load each full
// 14-element column into registers up front (independent loads pipeline;
// ~20% fewer LDS reads; no rolling-window dependency chain, no in-place
// read-after-write subtlety). Splat/decode/store identical to R11.
// ---------------------------------------------------------------------------
__global__ __launch_bounds__(256, 4)
void tile_persist(const float4* __restrict__ pts, const int* __restrict__ bcount,
                  const int* __restrict__ list, float* __restrict__ out)
{
    __shared__ float2 raw[4312];   // 34,496 B
    __shared__ int pf[17];

    const int t = threadIdx.x;
    if (t < 16) pf[t + 1] = bcount[t];
    if (t == 0) pf[0] = 0;
    __syncthreads();
    if (t == 0) {
        int s = 0;
        #pragma unroll
        for (int i = 1; i <= 16; ++i) { s += pf[i]; pf[i] = s; }
    }
    __syncthreads();
    const int total = pf[16];

    for (int idx = blockIdx.x; idx < total; idx += gridDim.x) {
        int bb = 0;
        #pragma unroll 1
        for (; bb < 15; ++bb) if (idx < pf[bb + 1]) break;
        const int code = list[bb * 2048 + (idx - pf[bb])];
        const int pair = code & 7;
        const int ty   = (code >> 3) & 15;
        const int tz   = (code >> 7) & 15;
        const int b    = code >> 11;
        const int Tx = pair * 16, Ty = ty * 8, Tz = tz * 8;

        float* ob = out + (((size_t)(b * NVOX + Tz) * NVOX + Ty) * NVOX + Tx);

        {   // zero the LDS tile (float4 fill)
            float4* rz = (float4*)raw;
            for (int u = t; u < 2156; u += 256) rz[u] = make_float4(0.f, 0.f, 0.f, 0.f);
        }
        __syncthreads();

        // scatter this batch's points (raw covers [T-3, T+{19,11,11}))
        const float4* pb = pts + b * NPT;
        for (int p = t; p < NPT; p += 256) {
            float4 pt = pb[p];
            float x0f = floorf(pt.x), y0f = floorf(pt.y), z0f = floorf(pt.z);
            int x0 = (int)x0f, y0 = (int)y0f, z0 = (int)z0f;
            int lx0 = x0 - Tx + 3, ly0 = y0 - Ty + 3, lz0 = z0 - Tz + 3;
            if (lx0 + 1 < 0 || lx0 > 21 || ly0 + 1 < 0 || ly0 > 13 ||
                lz0 + 1 < 0 || lz0 > 13) continue;
            float fx = pt.x - x0f, fy = pt.y - y0f, fz = pt.z - z0f;
            float val = pt.w;
            #pragma unroll
            for (int dz = 0; dz < 2; ++dz) {
                int zi = z0 + dz, lz = lz0 + dz;
                if ((unsigned)zi >= 128u || (unsigned)lz >= 14u) continue;
                float wz = dz ? fz : 1.f - fz;
                #pragma unroll
                for (int dy = 0; dy < 2; ++dy) {
                    int yi = y0 + dy, ly = ly0 + dy;
                    if ((unsigned)yi >= 128u || (unsigned)ly >= 14u) continue;
                    float wy = dy ? fy : 1.f - fy;
                    #pragma unroll
                    for (int dx = 0; dx < 2; ++dx) {
                        int xi = x0 + dx, lx = lx0 + dx;
                        if ((unsigned)xi >= 128u || (unsigned)lx >= 22u) continue;
                        float w = (dx ? fx : 1.f - fx) * wy * wz;
                        float2* cell = &raw[(lz * 14 + ly) * 22 + lx];
                        atomicAdd(&cell->x, w * val);
                        atomicAdd(&cell->y, w);
                    }
                }
            }
        }
        __syncthreads();

        // z-pass: columns (ly,lx); load full 14-column into regs, write 8
        for (int c = t; c < 308; c += 256) {
            float2 v[14];
            #pragma unroll
            for (int i = 0; i < 14; ++i) v[i] = raw[c + i * 308];
            #pragma unroll
            for (int z = 0; z < 8; ++z) {
                float cm1, c0, cp1; coef(Tz + z, cm1, c0, cp1);
                float sx = (v[z].x + v[z + 6].x) + 3.f * (v[z + 1].x + v[z + 5].x)
                         + cm1 * v[z + 2].x + c0 * v[z + 3].x + cp1 * v[z + 4].x;
                float sy = (v[z].y + v[z + 6].y) + 3.f * (v[z + 1].y + v[z + 5].y)
                         + cm1 * v[z + 2].y + c0 * v[z + 3].y + cp1 * v[z + 4].y;
                raw[c + z * 308] = f2(sx * (1.f / 27.f), sy * (1.f / 27.f));
            }
        }
        __syncthreads();

        // y-pass: columns (z,lx), z<8; load 14 at stride 22, write 8
        if (t < 176) {
            int z = t / 22, lx = t - z * 22;
            float2* base = &raw[z * 308 + lx];
            float2 v[14];
            #pragma unroll
            for (int i = 0; i < 14; ++i) v[i] = base[i * 22];
            #pragma unroll
            for (int y = 0; y < 8; ++y) {
                float cm1, c0, cp1; coef(Ty + y, cm1, c0, cp1);
                float sx = (v[y].x + v[y + 6].x) + 3.f * (v[y + 1].x + v[y + 5].x)
                         + cm1 * v[y + 2].x + c0 * v[y + 3].x + cp1 * v[y + 4].x;
                float sy = (v[y].y + v[y + 6].y) + 3.f * (v[y + 1].y + v[y + 5].y)
                         + cm1 * v[y + 2].y + c0 * v[y + 3].y + cp1 * v[y + 4].y;
                base[y * 22] = f2(sx * (1.f / 27.f), sy * (1.f / 27.f));
            }
        }
        __syncthreads();

        // x-pass + division: 2 threads per (z,y) row; load 14, emit 8
        if (t < 128) {
            int row = t >> 1, hx = t & 1;
            int z = row >> 3, y = row & 7;
            const float2* a = &raw[z * 308 + y * 22 + hx * 8];
            float2 v[14];
            #pragma unroll
            for (int i = 0; i < 14; ++i) v[i] = a[i];
            float res[8];
            #pragma unroll
            for (int i = 0; i < 8; ++i) {
                int x = hx * 8 + i;
                float cm1, c0, cp1; coef(Tx + x, cm1, c0, cp1);
                float sx = (v[i].x + v[i + 6].x) + 3.f * (v[i + 1].x + v[i + 5].x)
                         + cm1 * v[i + 2].x + c0 * v[i + 3].x + cp1 * v[i + 4].x;
                float sy = (v[i].y + v[i + 6].y) + 3.f * (v[i + 1].y + v[i + 5].y)
                         + cm1 * v[i + 2].y + c0 * v[i + 3].y + cp1 * v[i + 4].y;
                res[i] = (sx * (1.f / 27.f)) / (sy * (1.f / 27.f) + 0.001f);
            }
            float* orow = &ob[((size_t)z * NVOX + y) * NVOX + hx * 8];
            *(float4*)&orow[0] = make_float4(res[0], res[1], res[2], res[3]);
            *(float4*)&orow[4] = make_float4(res[4], res[5], res[6], res[7]);
        }
        __syncthreads();   // raw re-zeroed next iteration
    }
}

// ---------------------------------------------------------------------------
extern "C" void kernel_launch(void* const* d_in, const int* in_sizes, int n_in,
                              void* d_out, int out_size, void* d_ws, size_t ws_size,
                              hipStream_t stream)
{
    const float* q    = (const float*)d_in[0];
    const float* qval = (const float*)d_in[1];
    const float* w1   = (const float*)d_in[2];
    const float* b1   = (const float*)d_in[3];
    const float* w2   = (const float*)d_in[4];
    const float* b2   = (const float*)d_in[5];
    const float* w3   = (const float*)d_in[6];
    const float* b3   = (const float*)d_in[7];
    const float* w4   = (const float*)d_in[8];
    const float* b4   = (const float*)d_in[9];
    const float* w5   = (const float*)d_in[10];
    const float* b5   = (const float*)d_in[11];
    float* out = (float*)d_out;

    // ws layout:
    //   [0,       64)    bcount (16 ints, padded)
    //   [64,  131136)    list (16 x 2048 ints)
    //   [131136, 622656) pts  (16 x 1920 float4)
    int*    bcount = (int*)d_ws;
    int*    list   = (int*)((char*)d_ws + 64);
    float4* pts    = (float4*)((char*)d_ws + 131136);

    tail_zero_k<<<512, 1024, 0, stream>>>(q, w1, b1, qval, w2, b2, w3, b3,
                                          w4, b4, w5, b5, pts, bcount, list,
                                          (float4*)out);

    tile_persist<<<2048, 256, 0, stream>>>(pts, bcount, list, out);
}